// Round 2
// baseline (134.462 us; speedup 1.0000x reference)
//
#include <hip/hip_runtime.h>
#include <math.h>

namespace {

constexpr int kC = 16;                 // channels
constexpr int kB = 32;                 // rays
constexpr int kChunks = 128 * 128 * 16;  // 8-z chunks over the 128^3 grid

__device__ inline float readlane_f(float v, int lane) {
    return __int_as_float(__builtin_amdgcn_readlane(__float_as_int(v), lane));
}

__global__ void zero_kernel(float* __restrict__ out, int n) {
    int i = blockIdx.x * blockDim.x + threadIdx.x;
    if (i < n) out[i] = 0.0f;
}

__global__ __launch_bounds__(256)
void hpm_read_kernel(const float* __restrict__ memory,
                     const float* __restrict__ ray_o,
                     const float* __restrict__ ray_d,
                     float* __restrict__ out)
{
    const int gtid = blockIdx.x * 256 + threadIdx.x;   // chunk id, 0..262143
    const int col  = gtid >> 4;                        // column (x,y), 0..16383
    const int zb   = (gtid & 15) << 3;                 // z base of the 8-chunk
    const int idx0 = (col << 7) + zb;                  // linear grid index of z0
    const float px = (float)(col >> 7);
    const float py = (float)(col & 127);
    const float z0 = (float)zb;

    // Stage ray params across lanes: lane b holds ray b's (o, d).
    const int lane = threadIdx.x & 63;
    float q0 = 0.f, q1 = 0.f, q2 = 0.f, q3 = 0.f, q4 = 0.f, q5 = 0.f;
    if (lane < kB) {
        q0 = ray_o[3 * lane + 0]; q1 = ray_o[3 * lane + 1]; q2 = ray_o[3 * lane + 2];
        q3 = ray_d[3 * lane + 0]; q4 = ray_d[3 * lane + 1]; q5 = ray_d[3 * lane + 2];
    }

    const float4* __restrict__ mem4 = reinterpret_cast<const float4*>(memory);

    float a[kC];
    #pragma unroll
    for (int i = 0; i < kC; ++i) a[i] = 0.0f;

    for (int b = 0; b < kB; ++b) {
        // broadcast ray b to all lanes (wave-uniform -> SGPRs)
        const float ox  = readlane_f(q0, b), oy  = readlane_f(q1, b), oz  = readlane_f(q2, b);
        const float ddx = readlane_f(q3, b), ddy = readlane_f(q4, b), ddz = readlane_f(q5, b);

        const float dx = px - ox, dy = py - oy;
        const float c1 = fmaf(dx, ddx, dy * ddy);          // xy part of t
        const float dzc = z0 + 3.5f - oz;                  // chunk-center z offset
        const float tc = fmaf(dzc, ddz, c1);
        const float nb2c = fmaf(dzc, dzc, fmaf(dx, dx, dy * dy));
        const float r2c = fmaf(-tc, tc, nb2c);             // line-dist^2 at center

        // conservative chunk cull: point passes exact test only if
        // r_line <= 2.83 and t <= 32; center within +3.5 slack (z half-extent).
        bool anyhit = false;
        if (r2c < 40.5f && tc < 36.0f) {
            #pragma unroll
            for (int zz = 0; zz < 8; ++zz) {
                const float dzf = z0 + (float)zz - oz;
                const float t  = fmaf(dzf, ddz, c1);
                const float ex = fmaf(-t, ddx, dx);
                const float ey = fmaf(-t, ddy, dy);
                const float ez = fmaf(-t, ddz, dzf);
                const float r2 = fmaf(ex, ex, fmaf(ey, ey, ez * ez));
                const float arg = fmaf(-2.0f, r2, -0.5f * fmaxf(t, 0.0f));
                if (arg > -16.0f) {                        // e^-16 ~ 1e-7: negligible tail
                    const float k = __expf(arg);
                    const int base = (idx0 + zz) * 4;
                    const float4 m0 = mem4[base + 0];
                    const float4 m1 = mem4[base + 1];
                    const float4 m2 = mem4[base + 2];
                    const float4 m3 = mem4[base + 3];
                    a[ 0] = fmaf(k, m0.x, a[ 0]); a[ 1] = fmaf(k, m0.y, a[ 1]);
                    a[ 2] = fmaf(k, m0.z, a[ 2]); a[ 3] = fmaf(k, m0.w, a[ 3]);
                    a[ 4] = fmaf(k, m1.x, a[ 4]); a[ 5] = fmaf(k, m1.y, a[ 5]);
                    a[ 6] = fmaf(k, m1.z, a[ 6]); a[ 7] = fmaf(k, m1.w, a[ 7]);
                    a[ 8] = fmaf(k, m2.x, a[ 8]); a[ 9] = fmaf(k, m2.y, a[ 9]);
                    a[10] = fmaf(k, m2.z, a[10]); a[11] = fmaf(k, m2.w, a[11]);
                    a[12] = fmaf(k, m3.x, a[12]); a[13] = fmaf(k, m3.y, a[13]);
                    a[14] = fmaf(k, m3.z, a[14]); a[15] = fmaf(k, m3.w, a[15]);
                    anyhit = true;
                }
            }
        }

        // reduce + flush only in waves that touched ray b (~ a few % of wave×b)
        if (__ballot(anyhit) != 0ull) {
            #pragma unroll
            for (int i = 0; i < kC; ++i) {
                float v = a[i];
                v += __shfl_xor(v, 32); v += __shfl_xor(v, 16);
                v += __shfl_xor(v,  8); v += __shfl_xor(v,  4);
                v += __shfl_xor(v,  2); v += __shfl_xor(v,  1);
                if (lane == 0) unsafeAtomicAdd(out + b * kC + i, v);
                a[i] = 0.0f;   // reset for next ray
            }
        }
    }
}

} // namespace

extern "C" void kernel_launch(void* const* d_in, const int* in_sizes, int n_in,
                              void* d_out, int out_size, void* d_ws, size_t ws_size,
                              hipStream_t stream) {
    const float* memory = (const float*)d_in[0];
    // d_in[1] = grid : unused, coordinates are implied by the linear index
    const float* ray_o  = (const float*)d_in[2];
    const float* ray_d  = (const float*)d_in[3];
    float* out = (float*)d_out;

    zero_kernel<<<1, 512, 0, stream>>>(out, kB * kC);
    hpm_read_kernel<<<kChunks / 256, 256, 0, stream>>>(memory, ray_o, ray_d, out);
}

// Round 3
// 48.726 us; speedup vs baseline: 2.7596x; 2.7596x over previous
//
#include <hip/hip_runtime.h>
#include <math.h>

namespace {

constexpr int kC = 16;    // channels
constexpr int kB = 32;    // rays
// One wave per (ray, slab-along-dominant-axis): 32 * 128 = 4096 waves.
constexpr int kWaves = kB * 128;

__global__ void zero_kernel(float* __restrict__ out, int n) {
    int i = blockIdx.x * blockDim.x + threadIdx.x;
    if (i < n) out[i] = 0.0f;
}

__global__ __launch_bounds__(256)
void hpm_read_kernel(const float* __restrict__ memory,
                     const float* __restrict__ ray_o,
                     const float* __restrict__ ray_d,
                     float* __restrict__ out)
{
    const int wid  = __builtin_amdgcn_readfirstlane((int)(threadIdx.x >> 6));
    const int lane = (int)(threadIdx.x & 63);
    const int wtask = blockIdx.x * 4 + wid;        // 0..4095
    const int ray   = wtask >> 7;                  // 0..31
    const int slab  = wtask & 127;                 // coordinate on dominant axis

    // Ray params (wave-uniform index -> scalar loads)
    const float ox = ray_o[3 * ray + 0], oy = ray_o[3 * ray + 1], oz = ray_o[3 * ray + 2];
    const float dx = ray_d[3 * ray + 0], dy = ray_d[3 * ray + 1], dz = ray_d[3 * ray + 2];

    // Dominant axis a0 (|d_a0| >= 1/sqrt(3)); permute frame to (a0, a1, a2)
    const float adx = fabsf(dx), ady = fabsf(dy), adz = fabsf(dz);
    int a0;
    if (adx >= ady && adx >= adz) a0 = 0; else if (ady >= adz) a0 = 1; else a0 = 2;
    const float o0 = (a0 == 0) ? ox : ((a0 == 1) ? oy : oz);
    const float d0 = (a0 == 0) ? dx : ((a0 == 1) ? dy : dz);
    const float o1 = (a0 == 0) ? oy : ox;   // a1 = (a0==0) ? y : x
    const float d1 = (a0 == 0) ? dy : dx;
    const float o2 = (a0 == 2) ? oy : oz;   // a2 = (a0==2) ? y : z
    const float d2 = (a0 == 2) ? dy : dz;
    const int st0 = (a0 == 0) ? 16384 : ((a0 == 1) ? 128 : 1);
    const int st1 = (a0 == 0) ? 128 : 16384;
    const int st2 = (a0 == 2) ? 128 : 1;

    // Slab-plane / line intersection
    const float sa  = (float)slab;
    const float t_s = (sa - o0) / d0;
    const float c1  = fmaf(t_s, d1, o1);
    const float c2  = fmaf(t_s, d2, o2);

    // Conservative slab cull:
    //  - t(p) >= t_s - 6.4 for any candidate; decay kills arg when t > 32,
    //    so t_s > 38.5 => every candidate fails.
    //  - in-plane window is +-5.41 around center; center beyond [-5.5, 132.5]
    //    => no integer voxel can pass.
    const bool slab_ok = (fmaxf(t_s, 0.0f) < 38.5f) &&
                         (c1 > -5.5f) && (c1 < 132.5f) &&
                         (c2 > -5.5f) && (c2 < 132.5f);

    float a[kC];
    #pragma unroll
    for (int i = 0; i < kC; ++i) a[i] = 0.0f;
    bool hit = false;

    if (slab_ok) {
        const int r1 = (int)rintf(c1);
        const int r2i = (int)rintf(c2);
        const float4* __restrict__ mem4 = reinterpret_cast<const float4*>(memory);
        #pragma unroll
        for (int cc = 0; cc < 2; ++cc) {
            const int q = lane + cc * 64;          // candidate id in 11x11 window
            if (q < 121) {
                const int y = r1 + (q / 11) - 5;   // axis-a1 coordinate
                const int z = r2i + (q % 11) - 5;  // axis-a2 coordinate
                if ((unsigned)y < 128u && (unsigned)z < 128u) {
                    const float e0 = sa - o0;
                    const float e1 = (float)y - o1;
                    const float e2 = (float)z - o2;
                    const float t  = fmaf(e0, d0, fmaf(e1, d1, e2 * d2));
                    const float g0 = fmaf(-t, d0, e0);
                    const float g1 = fmaf(-t, d1, e1);
                    const float g2 = fmaf(-t, d2, e2);
                    const float rr = fmaf(g0, g0, fmaf(g1, g1, g2 * g2));
                    const float arg = fmaf(-2.0f, rr, -0.5f * fmaxf(t, 0.0f));
                    if (arg > -16.0f) {            // e^-16 tail is negligible
                        const float k = __expf(arg);
                        const int idx = slab * st0 + y * st1 + z * st2;
                        const float4 m0 = mem4[idx * 4 + 0];
                        const float4 m1 = mem4[idx * 4 + 1];
                        const float4 m2 = mem4[idx * 4 + 2];
                        const float4 m3 = mem4[idx * 4 + 3];
                        a[ 0] = fmaf(k, m0.x, a[ 0]); a[ 1] = fmaf(k, m0.y, a[ 1]);
                        a[ 2] = fmaf(k, m0.z, a[ 2]); a[ 3] = fmaf(k, m0.w, a[ 3]);
                        a[ 4] = fmaf(k, m1.x, a[ 4]); a[ 5] = fmaf(k, m1.y, a[ 5]);
                        a[ 6] = fmaf(k, m1.z, a[ 6]); a[ 7] = fmaf(k, m1.w, a[ 7]);
                        a[ 8] = fmaf(k, m2.x, a[ 8]); a[ 9] = fmaf(k, m2.y, a[ 9]);
                        a[10] = fmaf(k, m2.z, a[10]); a[11] = fmaf(k, m2.w, a[11]);
                        a[12] = fmaf(k, m3.x, a[12]); a[13] = fmaf(k, m3.y, a[13]);
                        a[14] = fmaf(k, m3.z, a[14]); a[15] = fmaf(k, m3.w, a[15]);
                        hit = true;
                    }
                }
            }
        }
    }

    if (__ballot(hit) != 0ull) {
        // Butterfly all-reduce each channel across the wave (static indexing only)
        #pragma unroll
        for (int c = 0; c < kC; ++c) {
            float v = a[c];
            v += __shfl_xor(v,  1); v += __shfl_xor(v,  2);
            v += __shfl_xor(v,  4); v += __shfl_xor(v,  8);
            v += __shfl_xor(v, 16); v += __shfl_xor(v, 32);
            a[c] = v;
        }
        if (lane == 0) {
            float* o = out + ray * kC;
            unsafeAtomicAdd(o +  0, a[ 0]); unsafeAtomicAdd(o +  1, a[ 1]);
            unsafeAtomicAdd(o +  2, a[ 2]); unsafeAtomicAdd(o +  3, a[ 3]);
            unsafeAtomicAdd(o +  4, a[ 4]); unsafeAtomicAdd(o +  5, a[ 5]);
            unsafeAtomicAdd(o +  6, a[ 6]); unsafeAtomicAdd(o +  7, a[ 7]);
            unsafeAtomicAdd(o +  8, a[ 8]); unsafeAtomicAdd(o +  9, a[ 9]);
            unsafeAtomicAdd(o + 10, a[10]); unsafeAtomicAdd(o + 11, a[11]);
            unsafeAtomicAdd(o + 12, a[12]); unsafeAtomicAdd(o + 13, a[13]);
            unsafeAtomicAdd(o + 14, a[14]); unsafeAtomicAdd(o + 15, a[15]);
        }
    }
}

} // namespace

extern "C" void kernel_launch(void* const* d_in, const int* in_sizes, int n_in,
                              void* d_out, int out_size, void* d_ws, size_t ws_size,
                              hipStream_t stream) {
    const float* memory = (const float*)d_in[0];
    // d_in[1] = grid : unused, coordinates are implied by the linear index
    const float* ray_o  = (const float*)d_in[2];
    const float* ray_d  = (const float*)d_in[3];
    float* out = (float*)d_out;

    zero_kernel<<<1, 512, 0, stream>>>(out, kB * kC);
    hpm_read_kernel<<<kWaves / 4, 256, 0, stream>>>(memory, ray_o, ray_d, out);
}

// Round 4
// 15.041 us; speedup vs baseline: 8.9397x; 3.2395x over previous
//
#include <hip/hip_runtime.h>
#include <math.h>

namespace {

constexpr int kC = 16;    // channels
constexpr int kB = 32;    // rays
constexpr int kSlabs = 128;
constexpr int kWaves = kB * kSlabs;    // one wave per (ray, slab) = 4096

// Stage 1: per-(ray,slab) wave computes the tube-window weighted sum and
// stores its 16 partial channel sums to a PRIVATE ws slot (no atomics).
__global__ __launch_bounds__(256)
void hpm_read_kernel(const float* __restrict__ memory,
                     const float* __restrict__ ray_o,
                     const float* __restrict__ ray_d,
                     float* __restrict__ ws)
{
    const int wid  = __builtin_amdgcn_readfirstlane((int)(threadIdx.x >> 6));
    const int lane = (int)(threadIdx.x & 63);
    const int wtask = blockIdx.x * 4 + wid;        // 0..4095
    const int ray   = wtask >> 7;                  // 0..31
    const int slab  = wtask & 127;                 // coordinate on dominant axis

    // Ray params (wave-uniform index -> scalar loads)
    const float ox = ray_o[3 * ray + 0], oy = ray_o[3 * ray + 1], oz = ray_o[3 * ray + 2];
    const float dx = ray_d[3 * ray + 0], dy = ray_d[3 * ray + 1], dz = ray_d[3 * ray + 2];

    // Dominant axis a0 (|d_a0| >= 1/sqrt(3)); permute frame to (a0, a1, a2)
    const float adx = fabsf(dx), ady = fabsf(dy), adz = fabsf(dz);
    int a0;
    if (adx >= ady && adx >= adz) a0 = 0; else if (ady >= adz) a0 = 1; else a0 = 2;
    const float o0 = (a0 == 0) ? ox : ((a0 == 1) ? oy : oz);
    const float d0 = (a0 == 0) ? dx : ((a0 == 1) ? dy : dz);
    const float o1 = (a0 == 0) ? oy : ox;   // a1 = (a0==0) ? y : x
    const float d1 = (a0 == 0) ? dy : dx;
    const float o2 = (a0 == 2) ? oy : oz;   // a2 = (a0==2) ? y : z
    const float d2 = (a0 == 2) ? dy : dz;
    const int st0 = (a0 == 0) ? 16384 : ((a0 == 1) ? 128 : 1);
    const int st1 = (a0 == 0) ? 128 : 16384;
    const int st2 = (a0 == 2) ? 128 : 1;

    // Slab-plane / line intersection
    const float sa  = (float)slab;
    const float t_s = (sa - o0) / d0;
    const float c1  = fmaf(t_s, d1, o1);
    const float c2  = fmaf(t_s, d2, o2);

    // Conservative slab cull (see round-3 notes): forward decay kills t_s>38.5;
    // in-plane footprint is +-5.41 around the center.
    const bool slab_ok = (fmaxf(t_s, 0.0f) < 38.5f) &&
                         (c1 > -5.5f) && (c1 < 132.5f) &&
                         (c2 > -5.5f) && (c2 < 132.5f);

    float a[kC];
    #pragma unroll
    for (int i = 0; i < kC; ++i) a[i] = 0.0f;
    bool hit = false;

    if (slab_ok) {
        const int r1  = (int)rintf(c1);
        const int r2i = (int)rintf(c2);
        const float4* __restrict__ mem4 = reinterpret_cast<const float4*>(memory);
        #pragma unroll
        for (int cc = 0; cc < 2; ++cc) {
            const int q = lane + cc * 64;          // candidate id in 11x11 window
            if (q < 121) {
                const int y = r1 + (q / 11) - 5;   // axis-a1 coordinate
                const int z = r2i + (q % 11) - 5;  // axis-a2 coordinate
                if ((unsigned)y < 128u && (unsigned)z < 128u) {
                    const float e0 = sa - o0;
                    const float e1 = (float)y - o1;
                    const float e2 = (float)z - o2;
                    const float t  = fmaf(e0, d0, fmaf(e1, d1, e2 * d2));
                    const float g0 = fmaf(-t, d0, e0);
                    const float g1 = fmaf(-t, d1, e1);
                    const float g2 = fmaf(-t, d2, e2);
                    const float rr = fmaf(g0, g0, fmaf(g1, g1, g2 * g2));
                    const float arg = fmaf(-2.0f, rr, -0.5f * fmaxf(t, 0.0f));
                    if (arg > -16.0f) {            // e^-16 tail is negligible
                        const float k = __expf(arg);
                        const int idx = slab * st0 + y * st1 + z * st2;
                        const float4 m0 = mem4[idx * 4 + 0];
                        const float4 m1 = mem4[idx * 4 + 1];
                        const float4 m2 = mem4[idx * 4 + 2];
                        const float4 m3 = mem4[idx * 4 + 3];
                        a[ 0] = fmaf(k, m0.x, a[ 0]); a[ 1] = fmaf(k, m0.y, a[ 1]);
                        a[ 2] = fmaf(k, m0.z, a[ 2]); a[ 3] = fmaf(k, m0.w, a[ 3]);
                        a[ 4] = fmaf(k, m1.x, a[ 4]); a[ 5] = fmaf(k, m1.y, a[ 5]);
                        a[ 6] = fmaf(k, m1.z, a[ 6]); a[ 7] = fmaf(k, m1.w, a[ 7]);
                        a[ 8] = fmaf(k, m2.x, a[ 8]); a[ 9] = fmaf(k, m2.y, a[ 9]);
                        a[10] = fmaf(k, m2.z, a[10]); a[11] = fmaf(k, m2.w, a[11]);
                        a[12] = fmaf(k, m3.x, a[12]); a[13] = fmaf(k, m3.y, a[13]);
                        a[14] = fmaf(k, m3.z, a[14]); a[15] = fmaf(k, m3.w, a[15]);
                        hit = true;
                    }
                }
            }
        }
    }

    // Wave-reduce only if any lane hit; ALWAYS store (ws starts poisoned).
    if (__ballot(hit) != 0ull) {
        #pragma unroll
        for (int c = 0; c < kC; ++c) {
            float v = a[c];
            v += __shfl_xor(v,  1); v += __shfl_xor(v,  2);
            v += __shfl_xor(v,  4); v += __shfl_xor(v,  8);
            v += __shfl_xor(v, 16); v += __shfl_xor(v, 32);
            a[c] = v;
        }
    }
    if (lane == 0) {
        float4* w4 = reinterpret_cast<float4*>(ws + wtask * kC);
        w4[0] = make_float4(a[ 0], a[ 1], a[ 2], a[ 3]);
        w4[1] = make_float4(a[ 4], a[ 5], a[ 6], a[ 7]);
        w4[2] = make_float4(a[ 8], a[ 9], a[10], a[11]);
        w4[3] = make_float4(a[12], a[13], a[14], a[15]);
    }
}

// Stage 2: out[ray*16+c] = sum over 128 slabs of ws[(ray*128+slab)*16+c]
__global__ __launch_bounds__(512)
void reduce_kernel(const float* __restrict__ ws, float* __restrict__ out)
{
    const int t = (int)threadIdx.x;            // 0..511 = (ray, c)
    const int ray = t >> 4, c = t & 15;
    const float* __restrict__ p = ws + ray * (kSlabs * kC) + c;
    float s0 = 0.f, s1 = 0.f, s2 = 0.f, s3 = 0.f;
    #pragma unroll
    for (int i = 0; i < kSlabs; i += 4) {
        s0 += p[(i + 0) * kC];
        s1 += p[(i + 1) * kC];
        s2 += p[(i + 2) * kC];
        s3 += p[(i + 3) * kC];
    }
    out[t] = (s0 + s1) + (s2 + s3);
}

} // namespace

extern "C" void kernel_launch(void* const* d_in, const int* in_sizes, int n_in,
                              void* d_out, int out_size, void* d_ws, size_t ws_size,
                              hipStream_t stream) {
    const float* memory = (const float*)d_in[0];
    // d_in[1] = grid : unused, coordinates are implied by the linear index
    const float* ray_o  = (const float*)d_in[2];
    const float* ray_d  = (const float*)d_in[3];
    float* out = (float*)d_out;
    float* ws  = (float*)d_ws;    // uses 4096*16*4 = 256 KB of scratch

    hpm_read_kernel<<<kWaves / 4, 256, 0, stream>>>(memory, ray_o, ray_d, ws);
    reduce_kernel<<<1, 512, 0, stream>>>(ws, out);
}